// Round 2
// baseline (157.394 us; speedup 1.0000x reference)
//
#include <hip/hip_runtime.h>

// DurationEncoding: idx = searchsorted(bin_edges, time_value, side='left');
// out[i,:] = embed_table[idx[i],:]   (N=1M, NUM_EDGES=100, VOCAB=101, DIM=128, fp32)
//
// Write-BW-bound (537 MB out). One thread per float4 of output.
// R2 change: compile-time F4=32 specialization -> row/chunk via shift/mask
// (R1 had a runtime 64-bit division per iteration on the critical path),
// and all-32-bit index math.

#define MAX_EDGES 128

__device__ __forceinline__ int lower_bound_lds(const float* s_edges, int num_edges, float v) {
    int lo = 0, hi = num_edges;
    while (lo < hi) {
        int mid = (lo + hi) >> 1;
        if (s_edges[mid] < v) lo = mid + 1; else hi = mid;
    }
    return lo;
}

// Specialized: DIM=128 -> 32 float4 per row (shift/mask indexing, 32-bit).
__global__ __launch_bounds__(256) void duration_encoding_f4_32(
    const float* __restrict__ time_value,
    const float* __restrict__ bin_edges,
    const float* __restrict__ embed_table,
    float* __restrict__ out,
    unsigned int n, int num_edges)
{
    __shared__ float s_edges[MAX_EDGES];
    for (int i = threadIdx.x; i < num_edges; i += blockDim.x)
        s_edges[i] = bin_edges[i];
    __syncthreads();

    const unsigned int total  = n << 5;                 // n * 32 float4s
    const unsigned int stride = gridDim.x * blockDim.x;
    const float4* table4 = (const float4*)embed_table;
    float4* out4 = (float4*)out;

    for (unsigned int j = blockIdx.x * blockDim.x + threadIdx.x;
         j < total; j += stride) {
        unsigned int row = j >> 5;
        unsigned int c4  = j & 31u;

        float v = time_value[row];                      // broadcast per 32-lane group
        int lo = lower_bound_lds(s_edges, num_edges, v);

        out4[j] = table4[((unsigned int)lo << 5) + c4];
    }
}

// Generic fallback (any DIM divisible by 4).
__global__ __launch_bounds__(256) void duration_encoding_generic(
    const float* __restrict__ time_value,
    const float* __restrict__ bin_edges,
    const float* __restrict__ embed_table,
    float* __restrict__ out,
    unsigned int n, int num_edges, unsigned int f4_per_row)
{
    __shared__ float s_edges[MAX_EDGES];
    for (int i = threadIdx.x; i < num_edges; i += blockDim.x)
        s_edges[i] = bin_edges[i];
    __syncthreads();

    const unsigned long long total  = (unsigned long long)n * f4_per_row;
    const unsigned long long stride = (unsigned long long)gridDim.x * blockDim.x;
    const float4* table4 = (const float4*)embed_table;
    float4* out4 = (float4*)out;

    for (unsigned long long j = (unsigned long long)blockIdx.x * blockDim.x + threadIdx.x;
         j < total; j += stride) {
        unsigned int row = (unsigned int)(j / f4_per_row);
        unsigned int c4  = (unsigned int)(j - (unsigned long long)row * f4_per_row);
        float v = time_value[row];
        int lo = lower_bound_lds(s_edges, num_edges, v);
        out4[j] = table4[(unsigned long long)lo * f4_per_row + c4];
    }
}

extern "C" void kernel_launch(void* const* d_in, const int* in_sizes, int n_in,
                              void* d_out, int out_size, void* d_ws, size_t ws_size,
                              hipStream_t stream) {
    const float* time_value  = (const float*)d_in[0];
    const float* bin_edges   = (const float*)d_in[1];
    const float* embed_table = (const float*)d_in[2];
    float* out = (float*)d_out;

    const unsigned int n         = (unsigned int)in_sizes[0];
    const int          num_edges = in_sizes[1];
    const unsigned int dim       = (unsigned int)(out_size / in_sizes[0]);
    const unsigned int f4_per_row = dim / 4;

    const int block = 256;

    if (f4_per_row == 32u) {
        const unsigned int total = n << 5;
        unsigned int blocks_needed = (total + block - 1) / block;
        int grid = (int)(blocks_needed < 2048u ? blocks_needed : 2048u);
        duration_encoding_f4_32<<<grid, block, 0, stream>>>(
            time_value, bin_edges, embed_table, out, n, num_edges);
    } else {
        const unsigned long long total = (unsigned long long)n * f4_per_row;
        unsigned long long blocks_needed = (total + block - 1) / block;
        int grid = (int)(blocks_needed < 2048ull ? blocks_needed : 2048ull);
        duration_encoding_generic<<<grid, block, 0, stream>>>(
            time_value, bin_edges, embed_table, out, n, num_edges, f4_per_row);
    }
}

// Round 3
// 119.510 us; speedup vs baseline: 1.3170x; 1.3170x over previous
//
#include <hip/hip_runtime.h>

// DurationEncoding: idx = searchsorted(bin_edges, time_value, 'left'); out = embed_table[idx]
// N=1M, NUM_EDGES=100, VOCAB=101, DIM=128, fp32. Write-BW-bound (537 MB out).
//
// R3: two-kernel split. K1: branchless searchsorted -> idx[] in d_ws (4 MB).
// K2: pure gather, 4 independent float4 load/store pairs per thread (short
// dependency chain + 4x MLP; every store instr covers 8 full 128B lines).
// R2's fused kernel kept as fallback (ws too small / generic DIM).

#define MAX_EDGES 128
#define PAD_INF 3.402823466e+38f

// ---------- Kernel 1: idx = lower_bound(edges, v) ----------
__global__ __launch_bounds__(256) void compute_idx_kernel(
    const float* __restrict__ time_value,
    const float* __restrict__ bin_edges,
    int* __restrict__ idx,
    unsigned int n, int num_edges)
{
    __shared__ float s_edges[MAX_EDGES];
    if (threadIdx.x < MAX_EDGES)
        s_edges[threadIdx.x] = (threadIdx.x < (unsigned)num_edges)
                                   ? bin_edges[threadIdx.x] : PAD_INF;
    __syncthreads();

    const unsigned int stride = gridDim.x * blockDim.x;
    for (unsigned int i = blockIdx.x * blockDim.x + threadIdx.x;
         i < n; i += stride) {
        float v = time_value[i];
        int lo = 0;
        #pragma unroll
        for (int step = 64; step > 0; step >>= 1)
            lo += (s_edges[lo + step - 1] < v) ? step : 0;   // branchless lower_bound over 128 (padded +INF)
        idx[i] = lo;
    }
}

// ---------- Kernel 2: gather, DIM=128 (32 float4/row), 4 f4 per thread ----------
__global__ __launch_bounds__(256) void gather_f4_32(
    const int* __restrict__ idx,
    const float* __restrict__ embed_table,
    float* __restrict__ out,
    unsigned int n)
{
    const float4* t4 = (const float4*)embed_table;
    float4* o4 = (float4*)out;

    const unsigned int total  = n << 3;                 // 8 thread-groups per row
    const unsigned int stride = gridDim.x * blockDim.x;

    for (unsigned int j = blockIdx.x * blockDim.x + threadIdx.x;
         j < total; j += stride) {
        unsigned int row = j >> 3;
        unsigned int o   = j & 7u;
        unsigned int lo  = (unsigned int)idx[row];      // 8 distinct addrs/wave, L2-hot
        unsigned int tb  = (lo  << 5) + o;
        unsigned int ob  = (row << 5) + o;
        // 4 independent load/store pairs (chunks o, o+8, o+16, o+24)
        float4 a = t4[tb];
        float4 b = t4[tb + 8];
        float4 c = t4[tb + 16];
        float4 d = t4[tb + 24];
        o4[ob]      = a;
        o4[ob + 8]  = b;
        o4[ob + 16] = c;
        o4[ob + 24] = d;
    }
}

// ---------- Fallback: fused (R2), generic ----------
__device__ __forceinline__ int lower_bound_lds(const float* s_edges, int num_edges, float v) {
    int lo = 0, hi = num_edges;
    while (lo < hi) {
        int mid = (lo + hi) >> 1;
        if (s_edges[mid] < v) lo = mid + 1; else hi = mid;
    }
    return lo;
}

__global__ __launch_bounds__(256) void duration_encoding_generic(
    const float* __restrict__ time_value,
    const float* __restrict__ bin_edges,
    const float* __restrict__ embed_table,
    float* __restrict__ out,
    unsigned int n, int num_edges, unsigned int f4_per_row)
{
    __shared__ float s_edges[MAX_EDGES];
    for (int i = threadIdx.x; i < num_edges; i += blockDim.x)
        s_edges[i] = bin_edges[i];
    __syncthreads();

    const unsigned long long total  = (unsigned long long)n * f4_per_row;
    const unsigned long long stride = (unsigned long long)gridDim.x * blockDim.x;
    const float4* table4 = (const float4*)embed_table;
    float4* out4 = (float4*)out;

    for (unsigned long long j = (unsigned long long)blockIdx.x * blockDim.x + threadIdx.x;
         j < total; j += stride) {
        unsigned int row = (unsigned int)(j / f4_per_row);
        unsigned int c4  = (unsigned int)(j - (unsigned long long)row * f4_per_row);
        float v = time_value[row];
        int lo = lower_bound_lds(s_edges, num_edges, v);
        out4[j] = table4[(unsigned long long)lo * f4_per_row + c4];
    }
}

extern "C" void kernel_launch(void* const* d_in, const int* in_sizes, int n_in,
                              void* d_out, int out_size, void* d_ws, size_t ws_size,
                              hipStream_t stream) {
    const float* time_value  = (const float*)d_in[0];
    const float* bin_edges   = (const float*)d_in[1];
    const float* embed_table = (const float*)d_in[2];
    float* out = (float*)d_out;

    const unsigned int n         = (unsigned int)in_sizes[0];
    const int          num_edges = in_sizes[1];
    const unsigned int dim       = (unsigned int)(out_size / in_sizes[0]);
    const unsigned int f4_per_row = dim / 4;

    const int block = 256;

    if (f4_per_row == 32u && num_edges <= MAX_EDGES && ws_size >= (size_t)n * 4) {
        int* idx = (int*)d_ws;

        unsigned int b1 = (n + block - 1) / block;
        int grid1 = (int)(b1 < 4096u ? b1 : 4096u);
        compute_idx_kernel<<<grid1, block, 0, stream>>>(
            time_value, bin_edges, idx, n, num_edges);

        const unsigned int total = n << 3;
        unsigned int b2 = (total + block - 1) / block;
        int grid2 = (int)(b2 < 2048u ? b2 : 2048u);
        gather_f4_32<<<grid2, block, 0, stream>>>(idx, embed_table, out, n);
    } else {
        const unsigned long long total = (unsigned long long)n * f4_per_row;
        unsigned long long bn = (total + block - 1) / block;
        int grid = (int)(bn < 2048ull ? bn : 2048ull);
        duration_encoding_generic<<<grid, block, 0, stream>>>(
            time_value, bin_edges, embed_table, out, n, num_edges, f4_per_row);
    }
}

// Round 4
// 109.950 us; speedup vs baseline: 1.4315x; 1.0870x over previous
//
#include <hip/hip_runtime.h>

// DurationEncoding: idx = searchsorted(bin_edges, time_value, 'left'); out = embed_table[idx]
// N=1M, NUM_EDGES=100, VOCAB=101, DIM=128, fp32. Write-BW-bound (537 MB out; roofline ~86 us).
//
// R4: (1) K1 vectorized 4 elems/thread (float4 in, int4 out, 4 parallel searches).
//     (2) K2 gather: thread handles 4 float4s at stride total4/4 -> every wave
//         store instruction is 1KB fully contiguous (2 whole rows); 4 independent
//         idx->table->store chains batched for MLP.

#define MAX_EDGES 128
#define PAD_INF 3.402823466e+38f

__device__ __forceinline__ int lb128(const float* s_edges, float v) {
    int lo = 0;
    #pragma unroll
    for (int step = 64; step > 0; step >>= 1)
        if (s_edges[lo + step - 1] < v) lo += step;   // branchless lower_bound, 128 padded
    return lo;
}

// ---------- Kernel 1: idx = lower_bound(edges, v), 4 elements/thread ----------
__global__ __launch_bounds__(256) void compute_idx_vec4(
    const float* __restrict__ time_value,
    const float* __restrict__ bin_edges,
    int* __restrict__ idx,
    unsigned int n, int num_edges)
{
    __shared__ float s_edges[MAX_EDGES];
    if (threadIdx.x < MAX_EDGES)
        s_edges[threadIdx.x] = (threadIdx.x < (unsigned)num_edges)
                                   ? bin_edges[threadIdx.x] : PAD_INF;
    __syncthreads();

    const unsigned int nvec = n >> 2;
    const unsigned int t = blockIdx.x * blockDim.x + threadIdx.x;
    if (t < nvec) {
        float4 v = ((const float4*)time_value)[t];
        int4 r;
        r.x = lb128(s_edges, v.x);
        r.y = lb128(s_edges, v.y);
        r.z = lb128(s_edges, v.z);
        r.w = lb128(s_edges, v.w);
        ((int4*)idx)[t] = r;
    }
    // tail (n not multiple of 4)
    if (t == 0) {
        for (unsigned int i = nvec << 2; i < n; ++i)
            idx[i] = lb128(s_edges, time_value[i]);
    }
}

// ---------- Kernel 2: gather, DIM=128. 4 float4s/thread at stride total4/4 ----------
__global__ __launch_bounds__(256) void gather_strided4(
    const int* __restrict__ idx,
    const float* __restrict__ embed_table,
    float* __restrict__ out,
    unsigned int T)                                   // T = n*8 threads; total4 = 4*T
{
    const float4* t4 = (const float4*)embed_table;
    float4* o4 = (float4*)out;

    const unsigned int t = blockIdx.x * blockDim.x + threadIdx.x;
    if (t >= T) return;

    const unsigned int j0 = t;
    const unsigned int j1 = t + T;
    const unsigned int j2 = t + 2u * T;
    const unsigned int j3 = t + 3u * T;

    // 4 independent idx loads (2 distinct addrs per wave per load)
    unsigned int r0 = (unsigned int)idx[j0 >> 5];
    unsigned int r1 = (unsigned int)idx[j1 >> 5];
    unsigned int r2 = (unsigned int)idx[j2 >> 5];
    unsigned int r3 = (unsigned int)idx[j3 >> 5];

    // 4 independent table loads (L1/L2-resident 52 KB table)
    float4 a = t4[(r0 << 5) + (j0 & 31u)];
    float4 b = t4[(r1 << 5) + (j1 & 31u)];
    float4 c = t4[(r2 << 5) + (j2 & 31u)];
    float4 d = t4[(r3 << 5) + (j3 & 31u)];

    // 4 stores, each wave-instruction 1KB fully contiguous
    o4[j0] = a;
    o4[j1] = b;
    o4[j2] = c;
    o4[j3] = d;
}

// ---------- Fallback: fused generic (any DIM % 4 == 0) ----------
__device__ __forceinline__ int lower_bound_lds(const float* s_edges, int num_edges, float v) {
    int lo = 0, hi = num_edges;
    while (lo < hi) {
        int mid = (lo + hi) >> 1;
        if (s_edges[mid] < v) lo = mid + 1; else hi = mid;
    }
    return lo;
}

__global__ __launch_bounds__(256) void duration_encoding_generic(
    const float* __restrict__ time_value,
    const float* __restrict__ bin_edges,
    const float* __restrict__ embed_table,
    float* __restrict__ out,
    unsigned int n, int num_edges, unsigned int f4_per_row)
{
    __shared__ float s_edges[MAX_EDGES];
    for (int i = threadIdx.x; i < num_edges; i += blockDim.x)
        s_edges[i] = bin_edges[i];
    __syncthreads();

    const unsigned long long total  = (unsigned long long)n * f4_per_row;
    const unsigned long long stride = (unsigned long long)gridDim.x * blockDim.x;
    const float4* table4 = (const float4*)embed_table;
    float4* out4 = (float4*)out;

    for (unsigned long long j = (unsigned long long)blockIdx.x * blockDim.x + threadIdx.x;
         j < total; j += stride) {
        unsigned int row = (unsigned int)(j / f4_per_row);
        unsigned int c4  = (unsigned int)(j - (unsigned long long)row * f4_per_row);
        float v = time_value[row];
        int lo = lower_bound_lds(s_edges, num_edges, v);
        out4[j] = table4[(unsigned long long)lo * f4_per_row + c4];
    }
}

extern "C" void kernel_launch(void* const* d_in, const int* in_sizes, int n_in,
                              void* d_out, int out_size, void* d_ws, size_t ws_size,
                              hipStream_t stream) {
    const float* time_value  = (const float*)d_in[0];
    const float* bin_edges   = (const float*)d_in[1];
    const float* embed_table = (const float*)d_in[2];
    float* out = (float*)d_out;

    const unsigned int n         = (unsigned int)in_sizes[0];
    const int          num_edges = in_sizes[1];
    const unsigned int dim       = (unsigned int)(out_size / in_sizes[0]);
    const unsigned int f4_per_row = dim / 4;

    const int block = 256;

    if (f4_per_row == 32u && num_edges <= MAX_EDGES && ws_size >= (size_t)n * 4) {
        int* idx = (int*)d_ws;

        const unsigned int nvec = n >> 2;
        unsigned int b1 = (nvec + block - 1) / block;
        if (b1 == 0) b1 = 1;
        compute_idx_vec4<<<(int)b1, block, 0, stream>>>(
            time_value, bin_edges, idx, n, num_edges);

        const unsigned int T = n << 3;                 // total4 / 4
        unsigned int b2 = (T + block - 1) / block;
        gather_strided4<<<(int)b2, block, 0, stream>>>(idx, embed_table, out, T);
    } else {
        const unsigned long long total = (unsigned long long)n * f4_per_row;
        unsigned long long bn = (total + block - 1) / block;
        int grid = (int)(bn < 2048ull ? bn : 2048ull);
        duration_encoding_generic<<<grid, block, 0, stream>>>(
            time_value, bin_edges, embed_table, out, n, num_edges, f4_per_row);
    }
}

// Round 5
// 104.876 us; speedup vs baseline: 1.5008x; 1.0484x over previous
//
#include <hip/hip_runtime.h>

// DurationEncoding: idx = searchsorted(bin_edges, time_value, 'left'); out = embed_table[idx]
// N=1M, NUM_EDGES=100, VOCAB=101, DIM=128, fp32. Write-BW-bound (537 MB out; roofline ~86 us).
//
// R5: single fused wave-cooperative kernel. Block = 256 threads = 256 rows.
//   Phase 1: thread i searches time_value[base+i] (LDS branchless lower_bound),
//            stores pre-scaled row offset (lo*32) in LDS.
//   Phase 2: 32 coalesced iterations emit the block's 128 KB of output:
//            per-wave {LDS idx (2 distinct addrs ~ broadcast), 512B-contiguous
//            table load (L1-hot), 1KB-contiguous store}, unroll 8 for MLP.
// Removes R4's idx HBM round-trip (8 MB), second launch, and K1 kernel.

#define MAX_EDGES 128
#define PAD_INF 3.402823466e+38f
#define ROWS_PER_BLOCK 256

__device__ __forceinline__ int lb128(const float* s_edges, float v) {
    int lo = 0;
    #pragma unroll
    for (int step = 64; step > 0; step >>= 1)
        if (s_edges[lo + step - 1] < v) lo += step;   // branchless lower_bound, 128 padded
    return lo;
}

// ---------- Fused kernel, DIM=128 (32 float4/row), 256 rows/block ----------
__global__ __launch_bounds__(256) void duration_encoding_fused(
    const float* __restrict__ time_value,
    const float* __restrict__ bin_edges,
    const float* __restrict__ embed_table,
    float* __restrict__ out,
    unsigned int n, int num_edges)
{
    __shared__ float s_edges[MAX_EDGES];
    __shared__ int   s_off[ROWS_PER_BLOCK];           // pre-scaled: idx*32 (float4 units)

    if (threadIdx.x < MAX_EDGES)
        s_edges[threadIdx.x] = (threadIdx.x < (unsigned)num_edges)
                                   ? bin_edges[threadIdx.x] : PAD_INF;
    __syncthreads();

    const unsigned int base = blockIdx.x * ROWS_PER_BLOCK;

    // ---- Phase 1: one search per thread ----
    {
        unsigned int r = base + threadIdx.x;
        float v = (r < n) ? time_value[r] : 0.0f;
        s_off[threadIdx.x] = lb128(s_edges, v) << 5;
    }
    __syncthreads();

    // ---- Phase 2: emit 256 rows as 32 coalesced 1KB/wave iterations ----
    const float4* t4 = (const float4*)embed_table;
    float4* o4 = (float4*)out;
    const unsigned int base4 = base << 5;             // block's first float4 index

    if (base + ROWS_PER_BLOCK <= n) {                 // fast path (no guards)
        #pragma unroll 8
        for (int k = 0; k < 32; ++k) {
            unsigned int j = ((unsigned int)k << 8) + threadIdx.x;  // 0..8191
            int roff = s_off[j >> 5];
            o4[base4 + j] = t4[roff + (int)(j & 31u)];
        }
    } else {                                          // guarded tail block
        unsigned int limit = (n - base) << 5;
        for (unsigned int j = threadIdx.x; j < limit; j += blockDim.x) {
            int roff = s_off[j >> 5];
            o4[base4 + j] = t4[roff + (int)(j & 31u)];
        }
    }
}

// ---------- Fallback: fused generic (any DIM % 4 == 0) ----------
__device__ __forceinline__ int lower_bound_lds(const float* s_edges, int num_edges, float v) {
    int lo = 0, hi = num_edges;
    while (lo < hi) {
        int mid = (lo + hi) >> 1;
        if (s_edges[mid] < v) lo = mid + 1; else hi = mid;
    }
    return lo;
}

__global__ __launch_bounds__(256) void duration_encoding_generic(
    const float* __restrict__ time_value,
    const float* __restrict__ bin_edges,
    const float* __restrict__ embed_table,
    float* __restrict__ out,
    unsigned int n, int num_edges, unsigned int f4_per_row)
{
    __shared__ float s_edges[MAX_EDGES];
    for (int i = threadIdx.x; i < num_edges; i += blockDim.x)
        s_edges[i] = bin_edges[i];
    __syncthreads();

    const unsigned long long total  = (unsigned long long)n * f4_per_row;
    const unsigned long long stride = (unsigned long long)gridDim.x * blockDim.x;
    const float4* table4 = (const float4*)embed_table;
    float4* out4 = (float4*)out;

    for (unsigned long long j = (unsigned long long)blockIdx.x * blockDim.x + threadIdx.x;
         j < total; j += stride) {
        unsigned int row = (unsigned int)(j / f4_per_row);
        unsigned int c4  = (unsigned int)(j - (unsigned long long)row * f4_per_row);
        float v = time_value[row];
        int lo = lower_bound_lds(s_edges, num_edges, v);
        out4[j] = table4[(unsigned long long)lo * f4_per_row + c4];
    }
}

extern "C" void kernel_launch(void* const* d_in, const int* in_sizes, int n_in,
                              void* d_out, int out_size, void* d_ws, size_t ws_size,
                              hipStream_t stream) {
    const float* time_value  = (const float*)d_in[0];
    const float* bin_edges   = (const float*)d_in[1];
    const float* embed_table = (const float*)d_in[2];
    float* out = (float*)d_out;

    const unsigned int n         = (unsigned int)in_sizes[0];
    const int          num_edges = in_sizes[1];
    const unsigned int dim       = (unsigned int)(out_size / in_sizes[0]);
    const unsigned int f4_per_row = dim / 4;

    const int block = 256;

    if (f4_per_row == 32u && num_edges <= MAX_EDGES) {
        unsigned int grid = (n + ROWS_PER_BLOCK - 1) / ROWS_PER_BLOCK;
        duration_encoding_fused<<<(int)grid, block, 0, stream>>>(
            time_value, bin_edges, embed_table, out, n, num_edges);
    } else {
        const unsigned long long total = (unsigned long long)n * f4_per_row;
        unsigned long long bn = (total + block - 1) / block;
        int grid = (int)(bn < 2048ull ? bn : 2048ull);
        duration_encoding_generic<<<grid, block, 0, stream>>>(
            time_value, bin_edges, embed_table, out, n, num_edges, f4_per_row);
    }
}

// Round 7
// 103.555 us; speedup vs baseline: 1.5199x; 1.0128x over previous
//
#include <hip/hip_runtime.h>

// DurationEncoding: idx = searchsorted(bin_edges, time_value, 'left'); out = embed_table[idx]
// N=1M, NUM_EDGES=100, VOCAB=101, DIM=128, fp32. Write-BW-bound (537 MB out; roofline ~80-86 us).
//
// R7 = R6 with compile fix: __builtin_nontemporal_store needs a native clang
// vector type, not HIP_vector_type<float,4>. Use ext_vector_type(4) float.
// Structure: fused kernel, 512 rows/block (2 interleaved searches/thread),
// non-temporal 16B output stores.

#define MAX_EDGES 128
#define PAD_INF 3.402823466e+38f
#define ROWS_PER_BLOCK 512

typedef float vfloat4 __attribute__((ext_vector_type(4)));

__device__ __forceinline__ int lb128(const float* s_edges, float v) {
    int lo = 0;
    #pragma unroll
    for (int step = 64; step > 0; step >>= 1)
        if (s_edges[lo + step - 1] < v) lo += step;   // branchless lower_bound, 128 padded
    return lo;
}

// ---------- Fused kernel, DIM=128 (32 float4/row), 512 rows/block ----------
__global__ __launch_bounds__(256) void duration_encoding_fused(
    const float* __restrict__ time_value,
    const float* __restrict__ bin_edges,
    const float* __restrict__ embed_table,
    float* __restrict__ out,
    unsigned int n, int num_edges)
{
    __shared__ float s_edges[MAX_EDGES];
    __shared__ int   s_off[ROWS_PER_BLOCK];           // pre-scaled: idx*32 (float4 units)

    if (threadIdx.x < MAX_EDGES)
        s_edges[threadIdx.x] = (threadIdx.x < (unsigned)num_edges)
                                   ? bin_edges[threadIdx.x] : PAD_INF;
    __syncthreads();

    const unsigned int base = blockIdx.x * ROWS_PER_BLOCK;

    // ---- Phase 1: two searches per thread (independent chains, ILP) ----
    {
        unsigned int r0 = base + threadIdx.x;
        unsigned int r1 = base + 256u + threadIdx.x;
        float v0 = (r0 < n) ? time_value[r0] : 0.0f;
        float v1 = (r1 < n) ? time_value[r1] : 0.0f;
        int lo0 = 0, lo1 = 0;
        #pragma unroll
        for (int step = 64; step > 0; step >>= 1) {   // interleaved: 2 LDS reads in flight
            if (s_edges[lo0 + step - 1] < v0) lo0 += step;
            if (s_edges[lo1 + step - 1] < v1) lo1 += step;
        }
        s_off[threadIdx.x]        = lo0 << 5;
        s_off[threadIdx.x + 256]  = lo1 << 5;
    }
    __syncthreads();

    // ---- Phase 2: emit 512 rows as 64 coalesced 1KB/wave iterations ----
    const vfloat4* t4 = (const vfloat4*)embed_table;
    vfloat4* o4 = (vfloat4*)out;
    const unsigned int base4 = base << 5;             // block's first float4 index

    if (base + ROWS_PER_BLOCK <= n) {                 // fast path (no guards)
        #pragma unroll 8
        for (int k = 0; k < 64; ++k) {
            unsigned int j = ((unsigned int)k << 8) + threadIdx.x;  // 0..16383
            int roff = s_off[j >> 5];
            vfloat4 val = t4[roff + (int)(j & 31u)];
            __builtin_nontemporal_store(val, &o4[base4 + j]);
        }
    } else {                                          // guarded tail block
        unsigned int limit = (n - base) << 5;
        for (unsigned int j = threadIdx.x; j < limit; j += blockDim.x) {
            int roff = s_off[j >> 5];
            vfloat4 val = t4[roff + (int)(j & 31u)];
            __builtin_nontemporal_store(val, &o4[base4 + j]);
        }
    }
}

// ---------- Fallback: fused generic (any DIM % 4 == 0) ----------
__device__ __forceinline__ int lower_bound_lds(const float* s_edges, int num_edges, float v) {
    int lo = 0, hi = num_edges;
    while (lo < hi) {
        int mid = (lo + hi) >> 1;
        if (s_edges[mid] < v) lo = mid + 1; else hi = mid;
    }
    return lo;
}

__global__ __launch_bounds__(256) void duration_encoding_generic(
    const float* __restrict__ time_value,
    const float* __restrict__ bin_edges,
    const float* __restrict__ embed_table,
    float* __restrict__ out,
    unsigned int n, int num_edges, unsigned int f4_per_row)
{
    __shared__ float s_edges[MAX_EDGES];
    for (int i = threadIdx.x; i < num_edges; i += blockDim.x)
        s_edges[i] = bin_edges[i];
    __syncthreads();

    const unsigned long long total  = (unsigned long long)n * f4_per_row;
    const unsigned long long stride = (unsigned long long)gridDim.x * blockDim.x;
    const float4* table4 = (const float4*)embed_table;
    float4* out4 = (float4*)out;

    for (unsigned long long j = (unsigned long long)blockIdx.x * blockDim.x + threadIdx.x;
         j < total; j += stride) {
        unsigned int row = (unsigned int)(j / f4_per_row);
        unsigned int c4  = (unsigned int)(j - (unsigned long long)row * f4_per_row);
        float v = time_value[row];
        int lo = lower_bound_lds(s_edges, num_edges, v);
        out4[j] = table4[(unsigned long long)lo * f4_per_row + c4];
    }
}

extern "C" void kernel_launch(void* const* d_in, const int* in_sizes, int n_in,
                              void* d_out, int out_size, void* d_ws, size_t ws_size,
                              hipStream_t stream) {
    const float* time_value  = (const float*)d_in[0];
    const float* bin_edges   = (const float*)d_in[1];
    const float* embed_table = (const float*)d_in[2];
    float* out = (float*)d_out;

    const unsigned int n         = (unsigned int)in_sizes[0];
    const int          num_edges = in_sizes[1];
    const unsigned int dim       = (unsigned int)(out_size / in_sizes[0]);
    const unsigned int f4_per_row = dim / 4;

    const int block = 256;

    if (f4_per_row == 32u && num_edges <= MAX_EDGES) {
        unsigned int grid = (n + ROWS_PER_BLOCK - 1) / ROWS_PER_BLOCK;
        duration_encoding_fused<<<(int)grid, block, 0, stream>>>(
            time_value, bin_edges, embed_table, out, n, num_edges);
    } else {
        const unsigned long long total = (unsigned long long)n * f4_per_row;
        unsigned long long bn = (total + block - 1) / block;
        int grid = (int)(bn < 2048ull ? bn : 2048ull);
        duration_encoding_generic<<<grid, block, 0, stream>>>(
            time_value, bin_edges, embed_table, out, n, num_edges, f4_per_row);
    }
}

// Round 8
// 100.344 us; speedup vs baseline: 1.5685x; 1.0320x over previous
//
#include <hip/hip_runtime.h>

// DurationEncoding: idx = searchsorted(bin_edges, time_value, 'left'); out = embed_table[idx]
// N=1M, NUM_EDGES=100, VOCAB=101, DIM=128, fp32. Write-BW-bound (537 MB out; roofline ~80-86 us).
//
// R8 = R7 with ONE change: plain stores instead of __builtin_nontemporal_store
// (A/B to isolate the nt flag; fill kernels hit 6.7 TB/s with plain stores,
// and if L3 is memory-side write-coalescing, nt's no-allocate may cost BW).

#define MAX_EDGES 128
#define PAD_INF 3.402823466e+38f
#define ROWS_PER_BLOCK 512

typedef float vfloat4 __attribute__((ext_vector_type(4)));

__device__ __forceinline__ int lb128(const float* s_edges, float v) {
    int lo = 0;
    #pragma unroll
    for (int step = 64; step > 0; step >>= 1)
        if (s_edges[lo + step - 1] < v) lo += step;   // branchless lower_bound, 128 padded
    return lo;
}

// ---------- Fused kernel, DIM=128 (32 float4/row), 512 rows/block ----------
__global__ __launch_bounds__(256) void duration_encoding_fused(
    const float* __restrict__ time_value,
    const float* __restrict__ bin_edges,
    const float* __restrict__ embed_table,
    float* __restrict__ out,
    unsigned int n, int num_edges)
{
    __shared__ float s_edges[MAX_EDGES];
    __shared__ int   s_off[ROWS_PER_BLOCK];           // pre-scaled: idx*32 (float4 units)

    if (threadIdx.x < MAX_EDGES)
        s_edges[threadIdx.x] = (threadIdx.x < (unsigned)num_edges)
                                   ? bin_edges[threadIdx.x] : PAD_INF;
    __syncthreads();

    const unsigned int base = blockIdx.x * ROWS_PER_BLOCK;

    // ---- Phase 1: two searches per thread (independent chains, ILP) ----
    {
        unsigned int r0 = base + threadIdx.x;
        unsigned int r1 = base + 256u + threadIdx.x;
        float v0 = (r0 < n) ? time_value[r0] : 0.0f;
        float v1 = (r1 < n) ? time_value[r1] : 0.0f;
        int lo0 = 0, lo1 = 0;
        #pragma unroll
        for (int step = 64; step > 0; step >>= 1) {   // interleaved: 2 LDS reads in flight
            if (s_edges[lo0 + step - 1] < v0) lo0 += step;
            if (s_edges[lo1 + step - 1] < v1) lo1 += step;
        }
        s_off[threadIdx.x]        = lo0 << 5;
        s_off[threadIdx.x + 256]  = lo1 << 5;
    }
    __syncthreads();

    // ---- Phase 2: emit 512 rows as 64 coalesced 1KB/wave iterations ----
    const vfloat4* t4 = (const vfloat4*)embed_table;
    vfloat4* o4 = (vfloat4*)out;
    const unsigned int base4 = base << 5;             // block's first float4 index

    if (base + ROWS_PER_BLOCK <= n) {                 // fast path (no guards)
        #pragma unroll 8
        for (int k = 0; k < 64; ++k) {
            unsigned int j = ((unsigned int)k << 8) + threadIdx.x;  // 0..16383
            int roff = s_off[j >> 5];
            o4[base4 + j] = t4[roff + (int)(j & 31u)];
        }
    } else {                                          // guarded tail block
        unsigned int limit = (n - base) << 5;
        for (unsigned int j = threadIdx.x; j < limit; j += blockDim.x) {
            int roff = s_off[j >> 5];
            o4[base4 + j] = t4[roff + (int)(j & 31u)];
        }
    }
}

// ---------- Fallback: fused generic (any DIM % 4 == 0) ----------
__device__ __forceinline__ int lower_bound_lds(const float* s_edges, int num_edges, float v) {
    int lo = 0, hi = num_edges;
    while (lo < hi) {
        int mid = (lo + hi) >> 1;
        if (s_edges[mid] < v) lo = mid + 1; else hi = mid;
    }
    return lo;
}

__global__ __launch_bounds__(256) void duration_encoding_generic(
    const float* __restrict__ time_value,
    const float* __restrict__ bin_edges,
    const float* __restrict__ embed_table,
    float* __restrict__ out,
    unsigned int n, int num_edges, unsigned int f4_per_row)
{
    __shared__ float s_edges[MAX_EDGES];
    for (int i = threadIdx.x; i < num_edges; i += blockDim.x)
        s_edges[i] = bin_edges[i];
    __syncthreads();

    const unsigned long long total  = (unsigned long long)n * f4_per_row;
    const unsigned long long stride = (unsigned long long)gridDim.x * blockDim.x;
    const float4* table4 = (const float4*)embed_table;
    float4* out4 = (float4*)out;

    for (unsigned long long j = (unsigned long long)blockIdx.x * blockDim.x + threadIdx.x;
         j < total; j += stride) {
        unsigned int row = (unsigned int)(j / f4_per_row);
        unsigned int c4  = (unsigned int)(j - (unsigned long long)row * f4_per_row);
        float v = time_value[row];
        int lo = lower_bound_lds(s_edges, num_edges, v);
        out4[j] = table4[(unsigned long long)lo * f4_per_row + c4];
    }
}

extern "C" void kernel_launch(void* const* d_in, const int* in_sizes, int n_in,
                              void* d_out, int out_size, void* d_ws, size_t ws_size,
                              hipStream_t stream) {
    const float* time_value  = (const float*)d_in[0];
    const float* bin_edges   = (const float*)d_in[1];
    const float* embed_table = (const float*)d_in[2];
    float* out = (float*)d_out;

    const unsigned int n         = (unsigned int)in_sizes[0];
    const int          num_edges = in_sizes[1];
    const unsigned int dim       = (unsigned int)(out_size / in_sizes[0]);
    const unsigned int f4_per_row = dim / 4;

    const int block = 256;

    if (f4_per_row == 32u && num_edges <= MAX_EDGES) {
        unsigned int grid = (n + ROWS_PER_BLOCK - 1) / ROWS_PER_BLOCK;
        duration_encoding_fused<<<(int)grid, block, 0, stream>>>(
            time_value, bin_edges, embed_table, out, n, num_edges);
    } else {
        const unsigned long long total = (unsigned long long)n * f4_per_row;
        unsigned long long bn = (total + block - 1) / block;
        int grid = (int)(bn < 2048ull ? bn : 2048ull);
        duration_encoding_generic<<<grid, block, 0, stream>>>(
            time_value, bin_edges, embed_table, out, n, num_edges, f4_per_row);
    }
}